// Round 11
// baseline (291.451 us; speedup 1.0000x reference)
//
#include <hip/hip_runtime.h>
#include <stdint.h>

#define CC 256
#define HH 80
#define WW 80
#define PP 6400          // 80*80
#define GG 16
#define GNCNT (16*6400)  // per (n,group): 16 channels * 6400 pixels
#define SAPAD 272        // sA row stride in u16 (padded 256->272)

using frag_ab = __attribute__((ext_vector_type(8))) short;   // 8 bf16 (4 VGPRs)
using frag_cd = __attribute__((ext_vector_type(4))) float;   // 4 fp32
typedef unsigned short u16;

__device__ __forceinline__ float b2f(u16 u) {
    union { float f; uint32_t i; } v; v.i = ((uint32_t)u) << 16; return v.f;
}
__device__ __forceinline__ u16 f2b(float f) {
    uint32_t x = __float_as_uint(f);
    return (u16)((x + 0x7fffu + ((x >> 16) & 1u)) >> 16);  // RNE
}
__device__ __forceinline__ float sigf(float x) { return 1.f / (1.f + __expf(-x)); }

// three weight matrices fp32 -> bf16, one launch.  grid 192.
__global__ __launch_bounds__(256) void cvt3_kernel(
    const float* __restrict__ s0, const float* __restrict__ s1,
    const float* __restrict__ s2,
    u16* __restrict__ d0, u16* __restrict__ d1, u16* __restrict__ d2)
{
    const int blk = blockIdx.x >> 6;
    const int i = (blockIdx.x & 63) * 256 + threadIdx.x;   // < 16384
    const float* s = (blk == 0) ? s0 : (blk == 1) ? s1 : s2;
    u16*         d = (blk == 0) ? d0 : (blk == 1) ? d1 : d2;
    float4 v = ((const float4*)s)[i];
    ushort4 o;
    o.x = f2b(v.x); o.y = f2b(v.y); o.z = f2b(v.z); o.w = f2b(v.w);
    ((ushort4*)d)[i] = o;
}

// ---------------------------------------------------------------------------
// Round-11: gemm kernels byte-identical to round 10 (standalone, proven).
// TLP bump on the under-gridded streaming kernels (they ran at 1.25-2.5
// blocks/CU — too few waves to hide ~900cy HBM latency):
//   gn1:  grid (80,8)->(80,8,2) c-halves, 1280 blocks
//   scol: iq 4->8 slices, 640 blocks (Scolp 8 slices, scolred sums 8)
//   dw:   grid (80,8)->(80,2,8) j-halves, 1280 blocks
// ---------------------------------------------------------------------------

// conv1: stages from fp32 x (transpose-convert fused) + GN1 partial stats.
__global__ __launch_bounds__(256, 3) void gemm0_kernel(
    const u16* __restrict__ Wb,      // [256][256] bf16
    u16* __restrict__ Out,           // [51200][256] bf16
    float* __restrict__ pstats,      // [800][32] per-block partials
    const float* __restrict__ Xf)    // x fp32 [n][c][p]
{
    __shared__ __align__(16) u16 sA[64 * SAPAD];   // 34,816 B

    const int t    = threadIdx.x;
    const int lane = t & 63;
    const int wave = t >> 6;
    const int m    = lane & 15;
    const int q    = lane >> 4;
    const int mt   = blockIdx.x;
    const int m0   = mt * 64;
    const int n    = mt / 100;
    const int o0w  = wave * 64;

    {   // stage from x fp32 [c][p]: transpose-convert into sA[p][c]
        const int cl = t >> 2, pq = t & 3;
        const int p0 = m0 - n * PP;
        #pragma unroll
        for (int cb = 0; cb < 4; cb++) {
            const int c = cb * 64 + cl;
            const float* row = Xf + ((size_t)(n * CC + c)) * PP + p0 + pq * 16;
            #pragma unroll
            for (int u = 0; u < 4; u++) {
                float4 v = ((const float4*)(row + u * 4))[0];
                const int pp = pq * 16 + u * 4;
                sA[(pp + 0) * SAPAD + c] = f2b(v.x);
                sA[(pp + 1) * SAPAD + c] = f2b(v.y);
                sA[(pp + 2) * SAPAD + c] = f2b(v.z);
                sA[(pp + 3) * SAPAD + c] = f2b(v.w);
            }
        }
    }
    __syncthreads();

    frag_cd acc[4][4];
    #pragma unroll
    for (int ms = 0; ms < 4; ms++)
        #pragma unroll
        for (int j = 0; j < 4; j++)
            #pragma unroll
            for (int k = 0; k < 4; k++) acc[ms][j][k] = 0.f;

    const u16* wl = Wb + (size_t)(o0w + m) * CC + q * 8;

    #pragma unroll
    for (int jh = 0; jh < 2; jh++) {
        frag_ab wf[2][8];
        #pragma unroll
        for (int jj = 0; jj < 2; jj++)
            #pragma unroll
            for (int kc = 0; kc < 8; kc++)
                wf[jj][kc] = *(const frag_ab*)(wl + (size_t)((jh * 2 + jj) * 16) * CC + kc * 32);
        #pragma unroll
        for (int jj = 0; jj < 2; jj++)
            #pragma unroll
            for (int kc = 0; kc < 8; kc++)
                asm volatile("" : "+v"(wf[jj][kc]));

        #pragma unroll
        for (int ms = 0; ms < 4; ms++) {
            #pragma unroll
            for (int kc = 0; kc < 8; kc++) {
                frag_ab af = *(const frag_ab*)(sA + (ms * 16 + m) * SAPAD + kc * 32 + q * 8);
                #pragma unroll
                for (int jj = 0; jj < 2; jj++)
                    acc[ms][jh * 2 + jj] = __builtin_amdgcn_mfma_f32_16x16x32_bf16(
                        af, wf[jj][kc], acc[ms][jh * 2 + jj], 0, 0, 0);
            }
        }
    }
    __syncthreads();

    #pragma unroll
    for (int j = 0; j < 4; j++) {
        float s = 0.f, sq = 0.f;
        #pragma unroll
        for (int ms = 0; ms < 4; ms++)
            #pragma unroll
            for (int r = 0; r < 4; r++) {
                float v = acc[ms][j][r];
                s += v; sq += v * v;
            }
        #pragma unroll
        for (int off = 32; off > 0; off >>= 1) {
            s  += __shfl_down(s, off);
            sq += __shfl_down(sq, off);
        }
        if (lane == 0) {
            float* p = pstats + (size_t)mt * 32;
            p[wave * 4 + j]      = s;
            p[16 + wave * 4 + j] = sq;
        }
    }
    u16* myT = sA + wave * 1152;
    #pragma unroll
    for (int ms = 0; ms < 4; ms++) {
        #pragma unroll
        for (int j = 0; j < 4; j++)
            #pragma unroll
            for (int r = 0; r < 4; r++)
                myT[(q * 4 + r) * 72 + j * 16 + m] = f2b(acc[ms][j][r]);
        #pragma unroll
        for (int u = 0; u < 2; u++) {
            const int rr = u * 8 + (lane >> 3);
            frag_ab v = *(const frag_ab*)(myT + rr * 72 + (lane & 7) * 8);
            *(frag_ab*)(Out + (size_t)(m0 + ms * 16 + rr) * CC + o0w + (lane & 7) * 8) = v;
        }
    }
}

// gate conv + fused-scan gating; h read from the staged LDS tile.
__global__ __launch_bounds__(256, 3) void gemm1_kernel(
    const u16* __restrict__ A,       // hs [51200][256] bf16
    const u16* __restrict__ Wb,
    u16* __restrict__ Out,
    const float* __restrict__ Srow,  // [8*80][256]
    const float* __restrict__ Scol,  // [8*80][256] (pre-reduced)
    const float* __restrict__ bgate) // [256]
{
    __shared__ __align__(16) u16 sA[64 * SAPAD];

    const int t    = threadIdx.x;
    const int lane = t & 63;
    const int wave = t >> 6;
    const int m    = lane & 15;
    const int q    = lane >> 4;
    const int mt   = blockIdx.x;
    const int m0   = mt * 64;
    const int n    = mt / 100;
    const int o0w  = wave * 64;

    {   // stage A chunk: 64 rows x 256 c, lane-contiguous bf16 loads
        const int row = t >> 2, qt = t & 3;
        const u16* g = A + (size_t)(m0 + row) * CC + qt * 64;
        u16* d = sA + row * SAPAD + qt * 64;
        #pragma unroll
        for (int i = 0; i < 8; i++)
            *(frag_ab*)(d + i * 8) = *(const frag_ab*)(g + i * 8);
    }
    __syncthreads();

    frag_cd acc[4][4];
    #pragma unroll
    for (int ms = 0; ms < 4; ms++)
        #pragma unroll
        for (int j = 0; j < 4; j++)
            #pragma unroll
            for (int k = 0; k < 4; k++) acc[ms][j][k] = 0.f;

    const u16* wl = Wb + (size_t)(o0w + m) * CC + q * 8;

    #pragma unroll
    for (int jh = 0; jh < 2; jh++) {
        frag_ab wf[2][8];
        #pragma unroll
        for (int jj = 0; jj < 2; jj++)
            #pragma unroll
            for (int kc = 0; kc < 8; kc++)
                wf[jj][kc] = *(const frag_ab*)(wl + (size_t)((jh * 2 + jj) * 16) * CC + kc * 32);
        #pragma unroll
        for (int jj = 0; jj < 2; jj++)
            #pragma unroll
            for (int kc = 0; kc < 8; kc++)
                asm volatile("" : "+v"(wf[jj][kc]));

        #pragma unroll
        for (int ms = 0; ms < 4; ms++) {
            #pragma unroll
            for (int kc = 0; kc < 8; kc++) {
                frag_ab af = *(const frag_ab*)(sA + (ms * 16 + m) * SAPAD + kc * 32 + q * 8);
                #pragma unroll
                for (int jj = 0; jj < 2; jj++)
                    acc[ms][jh * 2 + jj] = __builtin_amdgcn_mfma_f32_16x16x32_bf16(
                        af, wf[jj][kc], acc[ms][jh * 2 + jj], 0, 0, 0);
            }
        }
    }

    // prefetch gate's h values FROM sA before the epilogue slab clobbers it
    ushort4 hv[4][4];
    {
        const int rr0 = lane >> 4;
        const int cH  = o0w + (lane & 15) * 4;
        #pragma unroll
        for (int ms = 0; ms < 4; ms++)
            #pragma unroll
            for (int u = 0; u < 4; u++)
                hv[ms][u] = *(const ushort4*)(sA + (size_t)(ms * 16 + u * 4 + rr0) * SAPAD + cH);
    }
    __syncthreads();

    float* myG = (float*)sA + wave * 1152;   // 16x72 fp32
    float bg[4];
    #pragma unroll
    for (int j = 0; j < 4; j++) bg[j] = bgate[o0w + j * 16 + m];
    #pragma unroll
    for (int ms = 0; ms < 4; ms++) {
        #pragma unroll
        for (int j = 0; j < 4; j++)
            #pragma unroll
            for (int r = 0; r < 4; r++)
                myG[(q * 4 + r) * 72 + j * 16 + m] = sigf(acc[ms][j][r] + bg[j]);
        #pragma unroll
        for (int u = 0; u < 4; u++) {
            const int rr  = u * 4 + (lane >> 4);
            const int col = (lane & 15) * 4;
            float4 g4 = *(const float4*)(myG + rr * 72 + col);
            const int row = m0 + ms * 16 + rr;
            const int pl  = row - n * PP;
            const int pr  = pl / WW;
            const int pc  = pl - pr * WW;
            const int o   = o0w + col;
            ushort4 hq = hv[ms][u];
            float4  sr = *(const float4*)(Srow + (size_t)(n * HH + pr) * CC + o);
            float4  sc = *(const float4*)(Scol + (size_t)(n * HH + pc) * CC + o);
            ushort4 ov;
            ov.x = f2b(0.25f * (sr.x + sc.x + 2.f * b2f(hq.x)) * g4.x);
            ov.y = f2b(0.25f * (sr.y + sc.y + 2.f * b2f(hq.y)) * g4.y);
            ov.z = f2b(0.25f * (sr.z + sc.z + 2.f * b2f(hq.z)) * g4.z);
            ov.w = f2b(0.25f * (sr.w + sc.w + 2.f * b2f(hq.w)) * g4.w);
            *(ushort4*)(Out + (size_t)row * CC + o) = ov;
        }
    }
}

// conv3: plain bf16 stage + GN2 partial stats.
__global__ __launch_bounds__(256, 3) void gemm2_kernel(
    const u16* __restrict__ A,       // dwout [51200][256] bf16
    const u16* __restrict__ Wb,
    u16* __restrict__ Out,
    float* __restrict__ pstats)      // [800][32]
{
    __shared__ __align__(16) u16 sA[64 * SAPAD];

    const int t    = threadIdx.x;
    const int lane = t & 63;
    const int wave = t >> 6;
    const int m    = lane & 15;
    const int q    = lane >> 4;
    const int mt   = blockIdx.x;
    const int m0   = mt * 64;
    const int o0w  = wave * 64;

    {
        const int row = t >> 2, qt = t & 3;
        const u16* g = A + (size_t)(m0 + row) * CC + qt * 64;
        u16* d = sA + row * SAPAD + qt * 64;
        #pragma unroll
        for (int i = 0; i < 8; i++)
            *(frag_ab*)(d + i * 8) = *(const frag_ab*)(g + i * 8);
    }
    __syncthreads();

    frag_cd acc[4][4];
    #pragma unroll
    for (int ms = 0; ms < 4; ms++)
        #pragma unroll
        for (int j = 0; j < 4; j++)
            #pragma unroll
            for (int k = 0; k < 4; k++) acc[ms][j][k] = 0.f;

    const u16* wl = Wb + (size_t)(o0w + m) * CC + q * 8;

    #pragma unroll
    for (int jh = 0; jh < 2; jh++) {
        frag_ab wf[2][8];
        #pragma unroll
        for (int jj = 0; jj < 2; jj++)
            #pragma unroll
            for (int kc = 0; kc < 8; kc++)
                wf[jj][kc] = *(const frag_ab*)(wl + (size_t)((jh * 2 + jj) * 16) * CC + kc * 32);
        #pragma unroll
        for (int jj = 0; jj < 2; jj++)
            #pragma unroll
            for (int kc = 0; kc < 8; kc++)
                asm volatile("" : "+v"(wf[jj][kc]));

        #pragma unroll
        for (int ms = 0; ms < 4; ms++) {
            #pragma unroll
            for (int kc = 0; kc < 8; kc++) {
                frag_ab af = *(const frag_ab*)(sA + (ms * 16 + m) * SAPAD + kc * 32 + q * 8);
                #pragma unroll
                for (int jj = 0; jj < 2; jj++)
                    acc[ms][jh * 2 + jj] = __builtin_amdgcn_mfma_f32_16x16x32_bf16(
                        af, wf[jj][kc], acc[ms][jh * 2 + jj], 0, 0, 0);
            }
        }
    }
    __syncthreads();

    #pragma unroll
    for (int j = 0; j < 4; j++) {
        float s = 0.f, sq = 0.f;
        #pragma unroll
        for (int ms = 0; ms < 4; ms++)
            #pragma unroll
            for (int r = 0; r < 4; r++) {
                float v = acc[ms][j][r];
                s += v; sq += v * v;
            }
        #pragma unroll
        for (int off = 32; off > 0; off >>= 1) {
            s  += __shfl_down(s, off);
            sq += __shfl_down(sq, off);
        }
        if (lane == 0) {
            float* p = pstats + (size_t)mt * 32;
            p[wave * 4 + j]      = s;
            p[16 + wave * 4 + j] = sq;
        }
    }
    u16* myT = sA + wave * 1152;
    #pragma unroll
    for (int ms = 0; ms < 4; ms++) {
        #pragma unroll
        for (int j = 0; j < 4; j++)
            #pragma unroll
            for (int r = 0; r < 4; r++)
                myT[(q * 4 + r) * 72 + j * 16 + m] = f2b(acc[ms][j][r]);
        #pragma unroll
        for (int u = 0; u < 2; u++) {
            const int rr = u * 8 + (lane >> 3);
            frag_ab v = *(const frag_ab*)(myT + rr * 72 + (lane & 7) * 8);
            *(frag_ab*)(Out + (size_t)(m0 + ms * 16 + rr) * CC + o0w + (lane & 7) * 8) = v;
        }
    }
}

// GN1 + SiLU + Srow.  Round-11: c-split — block (i-row, n, chalf): 80 j x 128 c.
// 1280 blocks (was 640) for latency hiding.
__global__ __launch_bounds__(256) void gn1_kernel(
    const u16* __restrict__ c1, u16* __restrict__ hb,
    float* __restrict__ Srow,
    const float* __restrict__ pscr,   // [800][32]
    const float* __restrict__ g1, const float* __restrict__ b1)
{
    __shared__ float sred[16 * 128];
    __shared__ float sstat[32];
    const int i = blockIdx.x, n = blockIdx.y, ch = blockIdx.z;
    const int t = threadIdx.x;
    if (t < 32) {
        const int kind = t >> 4, g = t & 15;
        const float* p = pscr + (size_t)(n * 100) * 32 + kind * 16 + g;
        float s = 0.f;
        #pragma unroll 4
        for (int ii = 0; ii < 100; ii++) s += p[ii * 32];
        sstat[t] = s;
    }
    __syncthreads();

    const int jg = t >> 4, cc = t & 15;            // 16 j-rows x 16 c-chunks
    const int c8 = ch * 128 + cc * 8;
    const int g  = c8 >> 4;
    const float su   = sstat[g];
    const float sq   = sstat[16 + g];
    const float mean = su * (1.f / GNCNT);
    const float var  = sq * (1.f / GNCNT) - mean * mean;
    const float inv  = rsqrtf(var + 1e-5f);
    float a[8], b[8];
    #pragma unroll
    for (int k = 0; k < 8; k++) {
        a[k] = inv * g1[c8 + k];
        b[k] = b1[c8 + k] - mean * a[k];
    }
    float srow8[8];
    #pragma unroll
    for (int k = 0; k < 8; k++) srow8[k] = 0.f;

    const size_t base = (size_t)(n * PP + i * WW) * CC;
    for (int s = 0; s < 5; s++) {
        const int j = jg + s * 16;
        const u16* src = c1 + base + (size_t)j * CC + c8;
        u16*       dst = hb + base + (size_t)j * CC + c8;
        frag_ab v = *(const frag_ab*)src;
        frag_ab o;
        #pragma unroll
        for (int k = 0; k < 8; k++) {
            float xn = b2f((u16)v[k]) * a[k] + b[k];
            float hs = xn * sigf(xn);
            o[k] = (short)f2b(hs);
            srow8[k] += hs;
        }
        *(frag_ab*)dst = o;
    }
    #pragma unroll
    for (int k = 0; k < 8; k++) sred[jg * 128 + cc * 8 + k] = srow8[k];
    __syncthreads();
    if (t < 128) {
        float s = 0.f;
        #pragma unroll
        for (int k = 0; k < 16; k++) s += sred[k * 128 + t];
        Srow[(size_t)(n * HH + i) * CC + ch * 128 + t] = s;
    }
}

// Scolp[iq][n][j][c] = sum over 10 i's of hs.  8 atomic-free partial slices
// (was 4) — 640 blocks for latency hiding.
__global__ __launch_bounds__(256) void scol_kernel(
    const u16* __restrict__ hb, float* __restrict__ Scolp)
{
    const int jg = blockIdx.x, iq = blockIdx.y, n = blockIdx.z;
    const int t = threadIdx.x;
    const int js = t >> 5, cc = t & 31;
    const int j = jg * 8 + js, c8 = cc * 8;
    float acc8[8];
    #pragma unroll
    for (int k = 0; k < 8; k++) acc8[k] = 0.f;
    for (int s = 0; s < 10; s++) {
        const int i = iq * 10 + s;
        frag_ab v = *(const frag_ab*)(hb + (size_t)(n * PP + i * WW + j) * CC + c8);
        #pragma unroll
        for (int k = 0; k < 8; k++) acc8[k] += b2f((u16)v[k]);
    }
    float* dst = Scolp + ((size_t)((iq * 8 + n) * HH + j)) * CC + c8;
    *(float4*)(dst)     = make_float4(acc8[0], acc8[1], acc8[2], acc8[3]);
    *(float4*)(dst + 4) = make_float4(acc8[4], acc8[5], acc8[6], acc8[7]);
}

// Scol[n][j][c] = sum of 8 Scolp slices.  Block (j, n); thread = c.
__global__ __launch_bounds__(256) void scolred_kernel(
    const float* __restrict__ Scolp, float* __restrict__ Scol)
{
    const int j = blockIdx.x, n = blockIdx.y;
    const int c = threadIdx.x;
    float s = 0.f;
    #pragma unroll
    for (int iq = 0; iq < 8; iq++)
        s += Scolp[((size_t)((iq * 8 + n) * HH + j)) * CC + c];
    Scol[(size_t)(n * HH + j) * CC + c] = s;
}

// depthwise 3x3 zero-pad in [p][c] layout.  Round-11: j-split — block
// (i, jhalf, n); 1280 blocks.  8 channels/thread, 16B loads.
__global__ __launch_bounds__(256) void dw_kernel(
    const u16* __restrict__ gin, u16* __restrict__ dout,
    const float* __restrict__ wdw)
{
    __shared__ float sw[2304];   // [k][c]: sw[k*256+c] = wdw[c*9+k]
    const int i = blockIdx.x, jh = blockIdx.y, n = blockIdx.z;
    const int t = threadIdx.x;
    for (int u = t; u < 2304; u += 256) {
        const int c = u / 9, k = u - c * 9;
        sw[k * 256 + c] = wdw[u];
    }
    __syncthreads();

    const int jg = t >> 5, cc = t & 31;
    const int gc = cc * 8;
    float4 wla[9], wlb[9];
    #pragma unroll
    for (int k = 0; k < 9; k++) {
        wla[k] = *(const float4*)(sw + k * 256 + gc);
        wlb[k] = *(const float4*)(sw + k * 256 + gc + 4);
    }

    const size_t nbase = (size_t)n * PP * CC;
    for (int s = 0; s < 5; s++) {
        const int j = jh * 40 + jg + s * 8;
        float a0 = 0.f, a1 = 0.f, a2 = 0.f, a3 = 0.f;
        float a4 = 0.f, a5 = 0.f, a6 = 0.f, a7 = 0.f;
        #pragma unroll
        for (int di = -1; di <= 1; di++) {
            const int ii = i + di;
            if (ii < 0 || ii >= HH) continue;
            #pragma unroll
            for (int dj = -1; dj <= 1; dj++) {
                const int jj = j + dj;
                if (jj < 0 || jj >= WW) continue;
                frag_ab v = *(const frag_ab*)(gin + nbase + (size_t)(ii * WW + jj) * CC + gc);
                const int k = (di + 1) * 3 + (dj + 1);
                const float4 wa = wla[k], wb = wlb[k];
                a0 += wa.x * b2f((u16)v[0]); a1 += wa.y * b2f((u16)v[1]);
                a2 += wa.z * b2f((u16)v[2]); a3 += wa.w * b2f((u16)v[3]);
                a4 += wb.x * b2f((u16)v[4]); a5 += wb.y * b2f((u16)v[5]);
                a6 += wb.z * b2f((u16)v[6]); a7 += wb.w * b2f((u16)v[7]);
            }
        }
        frag_ab o;
        o[0] = (short)f2b(a0); o[1] = (short)f2b(a1);
        o[2] = (short)f2b(a2); o[3] = (short)f2b(a3);
        o[4] = (short)f2b(a4); o[5] = (short)f2b(a5);
        o[6] = (short)f2b(a6); o[7] = (short)f2b(a7);
        *(frag_ab*)(dout + nbase + (size_t)(i * WW + j) * CC + gc) = o;
    }
}

// GN2 + SiLU + transpose-out: Y [n][p][c] bf16 -> out [n][c][p] fp32.
__global__ __launch_bounds__(256) void gn2T_kernel(
    const u16* __restrict__ Y, float* __restrict__ out,
    const float* __restrict__ pscr,   // [800][32]
    const float* __restrict__ g2, const float* __restrict__ b2v)
{
    __shared__ u16 sT[64 * 72];
    __shared__ float sstat[32];
    const int p0 = blockIdx.x * 64, c0 = blockIdx.y * 64, n = blockIdx.z;
    const int t = threadIdx.x;
    if (t < 32) {
        const int kind = t >> 4, g = t & 15;
        const float* p = pscr + (size_t)(n * 100) * 32 + kind * 16 + g;
        float s = 0.f;
        #pragma unroll 4
        for (int ii = 0; ii < 100; ii++) s += p[ii * 32];
        sstat[t] = s;
    }
    {
        const int pl = t >> 2, cq = t & 3;
        const u16* row = Y + (size_t)(n * PP + p0 + pl) * CC + c0 + cq * 16;
        *(frag_ab*)(sT + pl * 72 + cq * 16)     = *(const frag_ab*)(row);
        *(frag_ab*)(sT + pl * 72 + cq * 16 + 8) = *(const frag_ab*)(row + 8);
    }
    __syncthreads();
    {
        const int cl = t >> 2, pq = t & 3;
        const int c = c0 + cl, g = c >> 4;
        const float su   = sstat[g];
        const float sq   = sstat[16 + g];
        const float mean = su * (1.f / GNCNT);
        const float var  = sq * (1.f / GNCNT) - mean * mean;
        const float inv  = rsqrtf(var + 1e-5f);
        const float a    = inv * g2[c];
        const float b    = b2v[c] - mean * a;
        float* orow = out + (size_t)(n * CC + c) * PP + p0 + pq * 16;
        #pragma unroll
        for (int u4 = 0; u4 < 4; u4++) {
            float4 o;
            float* op = (float*)&o;
            #pragma unroll
            for (int e = 0; e < 4; e++) {
                const int pp = pq * 16 + u4 * 4 + e;
                float xn = b2f(sT[pp * 72 + cl]) * a + b;
                op[e] = xn * sigf(xn);
            }
            ((float4*)(orow + u4 * 4))[0] = o;
        }
    }
}

extern "C" void kernel_launch(void* const* d_in, const int* in_sizes, int n_in,
                              void* d_out, int out_size, void* d_ws, size_t ws_size,
                              hipStream_t stream)
{
    const float* x      = (const float*)d_in[0];
    const float* w_pre  = (const float*)d_in[1];
    const float* g1     = (const float*)d_in[2];
    const float* b1     = (const float*)d_in[3];
    const float* w_gate = (const float*)d_in[4];
    const float* b_gate = (const float*)d_in[5];
    const float* w_dw   = (const float*)d_in[6];
    const float* w_pw   = (const float*)d_in[7];
    const float* g2     = (const float*)d_in[8];
    const float* b2     = (const float*)d_in[9];
    float* out = (float*)d_out;

    char* ws = (char*)d_ws;
    u16*   wb0   = (u16*)(ws);                      // 131,072 B
    u16*   wb1   = (u16*)(ws + 131072);             // 131,072 B
    u16*   wb2   = (u16*)(ws + 262144);             // 131,072 B
    float* Scolp = (float*)(ws + 393216);           // 5,242,880 B (8 slices)
    u16*   bufA  = (u16*)(ws + 26607616);           // 26,214,400 B
    u16*   bufB  = (u16*)(ws + 52822016);           // 26,214,400 B
    float* Srow  = (float*)(ws + 79036416);         // 655,360 B
    float* Scol  = (float*)(ws + 79691776);         // 655,360 B
    float* pscr0 = (float*)(ws + 80347136);         // 102,400 B
    float* pscr1 = (float*)(ws + 80449536);         // 102,400 B

    // weights (one launch)
    cvt3_kernel<<<192, 256, 0, stream>>>(w_pre, w_gate, w_pw, wb0, wb1, wb2);

    // conv1 (stages directly from fp32 x, transpose fused) + GN1 partial stats
    gemm0_kernel<<<800, 256, 0, stream>>>(wb0, bufA, pscr0, x);
    // GN1 + SiLU + Srow (c-split, 1280 blocks) -> hs in bufB
    gn1_kernel<<<dim3(80, 8, 2), 256, 0, stream>>>(bufA, bufB, Srow, pscr0, g1, b1);
    // Scol partial slices (8 slices, 640 blocks) + tiny reduce
    scol_kernel<<<dim3(10, 8, 8), 256, 0, stream>>>(bufB, Scolp);
    scolred_kernel<<<dim3(80, 8), 256, 0, stream>>>(Scolp, Scol);
    // gate conv + fused-scan gating (h from LDS tile) -> gated in bufA
    gemm1_kernel<<<800, 256, 0, stream>>>(bufB, wb1, bufA, Srow, Scol, b_gate);
    // depthwise 3x3 (j-split, 1280 blocks)
    dw_kernel<<<dim3(80, 2, 8), 256, 0, stream>>>(bufA, bufB, w_dw);
    // conv3 + GN2 partial stats
    gemm2_kernel<<<800, 256, 0, stream>>>(bufB, wb2, bufA, pscr1);
    // GN2 + SiLU -> fp32 out (transposed; stats reduce inlined)
    gn2T_kernel<<<dim3(100, 4, 8), 256, 0, stream>>>(bufA, out, pscr1, g2, b2);
}

// Round 12
// 276.822 us; speedup vs baseline: 1.0528x; 1.0528x over previous
//
#include <hip/hip_runtime.h>
#include <stdint.h>

#define CC 256
#define HH 80
#define WW 80
#define PP 6400          // 80*80
#define GG 16
#define GNCNT (16*6400)  // per (n,group): 16 channels * 6400 pixels
#define SAPAD 272        // sA row stride in u16 (padded 256->272)

using frag_ab = __attribute__((ext_vector_type(8))) short;   // 8 bf16 (4 VGPRs)
using frag_cd = __attribute__((ext_vector_type(4))) float;   // 4 fp32
typedef unsigned short u16;

__device__ __forceinline__ float b2f(u16 u) {
    union { float f; uint32_t i; } v; v.i = ((uint32_t)u) << 16; return v.f;
}
__device__ __forceinline__ u16 f2b(float f) {
    uint32_t x = __float_as_uint(f);
    return (u16)((x + 0x7fffu + ((x >> 16) & 1u)) >> 16);  // RNE
}
__device__ __forceinline__ float sigf(float x) { return 1.f / (1.f + __expf(-x)); }

// three weight matrices fp32 -> bf16, one launch.  grid 192.
__global__ __launch_bounds__(256) void cvt3_kernel(
    const float* __restrict__ s0, const float* __restrict__ s1,
    const float* __restrict__ s2,
    u16* __restrict__ d0, u16* __restrict__ d1, u16* __restrict__ d2)
{
    const int blk = blockIdx.x >> 6;
    const int i = (blockIdx.x & 63) * 256 + threadIdx.x;   // < 16384
    const float* s = (blk == 0) ? s0 : (blk == 1) ? s1 : s2;
    u16*         d = (blk == 0) ? d0 : (blk == 1) ? d1 : d2;
    float4 v = ((const float4*)s)[i];
    ushort4 o;
    o.x = f2b(v.x); o.y = f2b(v.y); o.z = f2b(v.z); o.w = f2b(v.w);
    ((ushort4*)d)[i] = o;
}

// ---------------------------------------------------------------------------
// Round-12: gemm kernels byte-identical to round 10/11 (standalone, proven).
// dw REVERTED to round-10 form — round-11's j-split broke the 3-row halo's
// L2 reuse (FETCH 26->38.9 MB, +15us).  gn1 c-split and scol 8-slice kept
// (round-11's regression attributes to dw; this bench isolates gn1/scol).
// ---------------------------------------------------------------------------

// conv1: stages from fp32 x (transpose-convert fused) + GN1 partial stats.
__global__ __launch_bounds__(256, 3) void gemm0_kernel(
    const u16* __restrict__ Wb,      // [256][256] bf16
    u16* __restrict__ Out,           // [51200][256] bf16
    float* __restrict__ pstats,      // [800][32] per-block partials
    const float* __restrict__ Xf)    // x fp32 [n][c][p]
{
    __shared__ __align__(16) u16 sA[64 * SAPAD];   // 34,816 B

    const int t    = threadIdx.x;
    const int lane = t & 63;
    const int wave = t >> 6;
    const int m    = lane & 15;
    const int q    = lane >> 4;
    const int mt   = blockIdx.x;
    const int m0   = mt * 64;
    const int n    = mt / 100;
    const int o0w  = wave * 64;

    {   // stage from x fp32 [c][p]: transpose-convert into sA[p][c]
        const int cl = t >> 2, pq = t & 3;
        const int p0 = m0 - n * PP;
        #pragma unroll
        for (int cb = 0; cb < 4; cb++) {
            const int c = cb * 64 + cl;
            const float* row = Xf + ((size_t)(n * CC + c)) * PP + p0 + pq * 16;
            #pragma unroll
            for (int u = 0; u < 4; u++) {
                float4 v = ((const float4*)(row + u * 4))[0];
                const int pp = pq * 16 + u * 4;
                sA[(pp + 0) * SAPAD + c] = f2b(v.x);
                sA[(pp + 1) * SAPAD + c] = f2b(v.y);
                sA[(pp + 2) * SAPAD + c] = f2b(v.z);
                sA[(pp + 3) * SAPAD + c] = f2b(v.w);
            }
        }
    }
    __syncthreads();

    frag_cd acc[4][4];
    #pragma unroll
    for (int ms = 0; ms < 4; ms++)
        #pragma unroll
        for (int j = 0; j < 4; j++)
            #pragma unroll
            for (int k = 0; k < 4; k++) acc[ms][j][k] = 0.f;

    const u16* wl = Wb + (size_t)(o0w + m) * CC + q * 8;

    #pragma unroll
    for (int jh = 0; jh < 2; jh++) {
        frag_ab wf[2][8];
        #pragma unroll
        for (int jj = 0; jj < 2; jj++)
            #pragma unroll
            for (int kc = 0; kc < 8; kc++)
                wf[jj][kc] = *(const frag_ab*)(wl + (size_t)((jh * 2 + jj) * 16) * CC + kc * 32);
        #pragma unroll
        for (int jj = 0; jj < 2; jj++)
            #pragma unroll
            for (int kc = 0; kc < 8; kc++)
                asm volatile("" : "+v"(wf[jj][kc]));

        #pragma unroll
        for (int ms = 0; ms < 4; ms++) {
            #pragma unroll
            for (int kc = 0; kc < 8; kc++) {
                frag_ab af = *(const frag_ab*)(sA + (ms * 16 + m) * SAPAD + kc * 32 + q * 8);
                #pragma unroll
                for (int jj = 0; jj < 2; jj++)
                    acc[ms][jh * 2 + jj] = __builtin_amdgcn_mfma_f32_16x16x32_bf16(
                        af, wf[jj][kc], acc[ms][jh * 2 + jj], 0, 0, 0);
            }
        }
    }
    __syncthreads();

    #pragma unroll
    for (int j = 0; j < 4; j++) {
        float s = 0.f, sq = 0.f;
        #pragma unroll
        for (int ms = 0; ms < 4; ms++)
            #pragma unroll
            for (int r = 0; r < 4; r++) {
                float v = acc[ms][j][r];
                s += v; sq += v * v;
            }
        #pragma unroll
        for (int off = 32; off > 0; off >>= 1) {
            s  += __shfl_down(s, off);
            sq += __shfl_down(sq, off);
        }
        if (lane == 0) {
            float* p = pstats + (size_t)mt * 32;
            p[wave * 4 + j]      = s;
            p[16 + wave * 4 + j] = sq;
        }
    }
    u16* myT = sA + wave * 1152;
    #pragma unroll
    for (int ms = 0; ms < 4; ms++) {
        #pragma unroll
        for (int j = 0; j < 4; j++)
            #pragma unroll
            for (int r = 0; r < 4; r++)
                myT[(q * 4 + r) * 72 + j * 16 + m] = f2b(acc[ms][j][r]);
        #pragma unroll
        for (int u = 0; u < 2; u++) {
            const int rr = u * 8 + (lane >> 3);
            frag_ab v = *(const frag_ab*)(myT + rr * 72 + (lane & 7) * 8);
            *(frag_ab*)(Out + (size_t)(m0 + ms * 16 + rr) * CC + o0w + (lane & 7) * 8) = v;
        }
    }
}

// gate conv + fused-scan gating; h read from the staged LDS tile.
__global__ __launch_bounds__(256, 3) void gemm1_kernel(
    const u16* __restrict__ A,       // hs [51200][256] bf16
    const u16* __restrict__ Wb,
    u16* __restrict__ Out,
    const float* __restrict__ Srow,  // [8*80][256]
    const float* __restrict__ Scol,  // [8*80][256] (pre-reduced)
    const float* __restrict__ bgate) // [256]
{
    __shared__ __align__(16) u16 sA[64 * SAPAD];

    const int t    = threadIdx.x;
    const int lane = t & 63;
    const int wave = t >> 6;
    const int m    = lane & 15;
    const int q    = lane >> 4;
    const int mt   = blockIdx.x;
    const int m0   = mt * 64;
    const int n    = mt / 100;
    const int o0w  = wave * 64;

    {   // stage A chunk: 64 rows x 256 c, lane-contiguous bf16 loads
        const int row = t >> 2, qt = t & 3;
        const u16* g = A + (size_t)(m0 + row) * CC + qt * 64;
        u16* d = sA + row * SAPAD + qt * 64;
        #pragma unroll
        for (int i = 0; i < 8; i++)
            *(frag_ab*)(d + i * 8) = *(const frag_ab*)(g + i * 8);
    }
    __syncthreads();

    frag_cd acc[4][4];
    #pragma unroll
    for (int ms = 0; ms < 4; ms++)
        #pragma unroll
        for (int j = 0; j < 4; j++)
            #pragma unroll
            for (int k = 0; k < 4; k++) acc[ms][j][k] = 0.f;

    const u16* wl = Wb + (size_t)(o0w + m) * CC + q * 8;

    #pragma unroll
    for (int jh = 0; jh < 2; jh++) {
        frag_ab wf[2][8];
        #pragma unroll
        for (int jj = 0; jj < 2; jj++)
            #pragma unroll
            for (int kc = 0; kc < 8; kc++)
                wf[jj][kc] = *(const frag_ab*)(wl + (size_t)((jh * 2 + jj) * 16) * CC + kc * 32);
        #pragma unroll
        for (int jj = 0; jj < 2; jj++)
            #pragma unroll
            for (int kc = 0; kc < 8; kc++)
                asm volatile("" : "+v"(wf[jj][kc]));

        #pragma unroll
        for (int ms = 0; ms < 4; ms++) {
            #pragma unroll
            for (int kc = 0; kc < 8; kc++) {
                frag_ab af = *(const frag_ab*)(sA + (ms * 16 + m) * SAPAD + kc * 32 + q * 8);
                #pragma unroll
                for (int jj = 0; jj < 2; jj++)
                    acc[ms][jh * 2 + jj] = __builtin_amdgcn_mfma_f32_16x16x32_bf16(
                        af, wf[jj][kc], acc[ms][jh * 2 + jj], 0, 0, 0);
            }
        }
    }

    // prefetch gate's h values FROM sA before the epilogue slab clobbers it
    ushort4 hv[4][4];
    {
        const int rr0 = lane >> 4;
        const int cH  = o0w + (lane & 15) * 4;
        #pragma unroll
        for (int ms = 0; ms < 4; ms++)
            #pragma unroll
            for (int u = 0; u < 4; u++)
                hv[ms][u] = *(const ushort4*)(sA + (size_t)(ms * 16 + u * 4 + rr0) * SAPAD + cH);
    }
    __syncthreads();

    float* myG = (float*)sA + wave * 1152;   // 16x72 fp32
    float bg[4];
    #pragma unroll
    for (int j = 0; j < 4; j++) bg[j] = bgate[o0w + j * 16 + m];
    #pragma unroll
    for (int ms = 0; ms < 4; ms++) {
        #pragma unroll
        for (int j = 0; j < 4; j++)
            #pragma unroll
            for (int r = 0; r < 4; r++)
                myG[(q * 4 + r) * 72 + j * 16 + m] = sigf(acc[ms][j][r] + bg[j]);
        #pragma unroll
        for (int u = 0; u < 4; u++) {
            const int rr  = u * 4 + (lane >> 4);
            const int col = (lane & 15) * 4;
            float4 g4 = *(const float4*)(myG + rr * 72 + col);
            const int row = m0 + ms * 16 + rr;
            const int pl  = row - n * PP;
            const int pr  = pl / WW;
            const int pc  = pl - pr * WW;
            const int o   = o0w + col;
            ushort4 hq = hv[ms][u];
            float4  sr = *(const float4*)(Srow + (size_t)(n * HH + pr) * CC + o);
            float4  sc = *(const float4*)(Scol + (size_t)(n * HH + pc) * CC + o);
            ushort4 ov;
            ov.x = f2b(0.25f * (sr.x + sc.x + 2.f * b2f(hq.x)) * g4.x);
            ov.y = f2b(0.25f * (sr.y + sc.y + 2.f * b2f(hq.y)) * g4.y);
            ov.z = f2b(0.25f * (sr.z + sc.z + 2.f * b2f(hq.z)) * g4.z);
            ov.w = f2b(0.25f * (sr.w + sc.w + 2.f * b2f(hq.w)) * g4.w);
            *(ushort4*)(Out + (size_t)row * CC + o) = ov;
        }
    }
}

// conv3: plain bf16 stage + GN2 partial stats.
__global__ __launch_bounds__(256, 3) void gemm2_kernel(
    const u16* __restrict__ A,       // dwout [51200][256] bf16
    const u16* __restrict__ Wb,
    u16* __restrict__ Out,
    float* __restrict__ pstats)      // [800][32]
{
    __shared__ __align__(16) u16 sA[64 * SAPAD];

    const int t    = threadIdx.x;
    const int lane = t & 63;
    const int wave = t >> 6;
    const int m    = lane & 15;
    const int q    = lane >> 4;
    const int mt   = blockIdx.x;
    const int m0   = mt * 64;
    const int o0w  = wave * 64;

    {
        const int row = t >> 2, qt = t & 3;
        const u16* g = A + (size_t)(m0 + row) * CC + qt * 64;
        u16* d = sA + row * SAPAD + qt * 64;
        #pragma unroll
        for (int i = 0; i < 8; i++)
            *(frag_ab*)(d + i * 8) = *(const frag_ab*)(g + i * 8);
    }
    __syncthreads();

    frag_cd acc[4][4];
    #pragma unroll
    for (int ms = 0; ms < 4; ms++)
        #pragma unroll
        for (int j = 0; j < 4; j++)
            #pragma unroll
            for (int k = 0; k < 4; k++) acc[ms][j][k] = 0.f;

    const u16* wl = Wb + (size_t)(o0w + m) * CC + q * 8;

    #pragma unroll
    for (int jh = 0; jh < 2; jh++) {
        frag_ab wf[2][8];
        #pragma unroll
        for (int jj = 0; jj < 2; jj++)
            #pragma unroll
            for (int kc = 0; kc < 8; kc++)
                wf[jj][kc] = *(const frag_ab*)(wl + (size_t)((jh * 2 + jj) * 16) * CC + kc * 32);
        #pragma unroll
        for (int jj = 0; jj < 2; jj++)
            #pragma unroll
            for (int kc = 0; kc < 8; kc++)
                asm volatile("" : "+v"(wf[jj][kc]));

        #pragma unroll
        for (int ms = 0; ms < 4; ms++) {
            #pragma unroll
            for (int kc = 0; kc < 8; kc++) {
                frag_ab af = *(const frag_ab*)(sA + (ms * 16 + m) * SAPAD + kc * 32 + q * 8);
                #pragma unroll
                for (int jj = 0; jj < 2; jj++)
                    acc[ms][jh * 2 + jj] = __builtin_amdgcn_mfma_f32_16x16x32_bf16(
                        af, wf[jj][kc], acc[ms][jh * 2 + jj], 0, 0, 0);
            }
        }
    }
    __syncthreads();

    #pragma unroll
    for (int j = 0; j < 4; j++) {
        float s = 0.f, sq = 0.f;
        #pragma unroll
        for (int ms = 0; ms < 4; ms++)
            #pragma unroll
            for (int r = 0; r < 4; r++) {
                float v = acc[ms][j][r];
                s += v; sq += v * v;
            }
        #pragma unroll
        for (int off = 32; off > 0; off >>= 1) {
            s  += __shfl_down(s, off);
            sq += __shfl_down(sq, off);
        }
        if (lane == 0) {
            float* p = pstats + (size_t)mt * 32;
            p[wave * 4 + j]      = s;
            p[16 + wave * 4 + j] = sq;
        }
    }
    u16* myT = sA + wave * 1152;
    #pragma unroll
    for (int ms = 0; ms < 4; ms++) {
        #pragma unroll
        for (int j = 0; j < 4; j++)
            #pragma unroll
            for (int r = 0; r < 4; r++)
                myT[(q * 4 + r) * 72 + j * 16 + m] = f2b(acc[ms][j][r]);
        #pragma unroll
        for (int u = 0; u < 2; u++) {
            const int rr = u * 8 + (lane >> 3);
            frag_ab v = *(const frag_ab*)(myT + rr * 72 + (lane & 7) * 8);
            *(frag_ab*)(Out + (size_t)(m0 + ms * 16 + rr) * CC + o0w + (lane & 7) * 8) = v;
        }
    }
}

// GN1 + SiLU + Srow.  c-split — block (i-row, n, chalf): 80 j x 128 c.
__global__ __launch_bounds__(256) void gn1_kernel(
    const u16* __restrict__ c1, u16* __restrict__ hb,
    float* __restrict__ Srow,
    const float* __restrict__ pscr,   // [800][32]
    const float* __restrict__ g1, const float* __restrict__ b1)
{
    __shared__ float sred[16 * 128];
    __shared__ float sstat[32];
    const int i = blockIdx.x, n = blockIdx.y, ch = blockIdx.z;
    const int t = threadIdx.x;
    if (t < 32) {
        const int kind = t >> 4, g = t & 15;
        const float* p = pscr + (size_t)(n * 100) * 32 + kind * 16 + g;
        float s = 0.f;
        #pragma unroll 4
        for (int ii = 0; ii < 100; ii++) s += p[ii * 32];
        sstat[t] = s;
    }
    __syncthreads();

    const int jg = t >> 4, cc = t & 15;            // 16 j-rows x 16 c-chunks
    const int c8 = ch * 128 + cc * 8;
    const int g  = c8 >> 4;
    const float su   = sstat[g];
    const float sq   = sstat[16 + g];
    const float mean = su * (1.f / GNCNT);
    const float var  = sq * (1.f / GNCNT) - mean * mean;
    const float inv  = rsqrtf(var + 1e-5f);
    float a[8], b[8];
    #pragma unroll
    for (int k = 0; k < 8; k++) {
        a[k] = inv * g1[c8 + k];
        b[k] = b1[c8 + k] - mean * a[k];
    }
    float srow8[8];
    #pragma unroll
    for (int k = 0; k < 8; k++) srow8[k] = 0.f;

    const size_t base = (size_t)(n * PP + i * WW) * CC;
    for (int s = 0; s < 5; s++) {
        const int j = jg + s * 16;
        const u16* src = c1 + base + (size_t)j * CC + c8;
        u16*       dst = hb + base + (size_t)j * CC + c8;
        frag_ab v = *(const frag_ab*)src;
        frag_ab o;
        #pragma unroll
        for (int k = 0; k < 8; k++) {
            float xn = b2f((u16)v[k]) * a[k] + b[k];
            float hs = xn * sigf(xn);
            o[k] = (short)f2b(hs);
            srow8[k] += hs;
        }
        *(frag_ab*)dst = o;
    }
    #pragma unroll
    for (int k = 0; k < 8; k++) sred[jg * 128 + cc * 8 + k] = srow8[k];
    __syncthreads();
    if (t < 128) {
        float s = 0.f;
        #pragma unroll
        for (int k = 0; k < 16; k++) s += sred[k * 128 + t];
        Srow[(size_t)(n * HH + i) * CC + ch * 128 + t] = s;
    }
}

// Scolp[iq][n][j][c] = sum over 10 i's of hs.  8 atomic-free partial slices.
__global__ __launch_bounds__(256) void scol_kernel(
    const u16* __restrict__ hb, float* __restrict__ Scolp)
{
    const int jg = blockIdx.x, iq = blockIdx.y, n = blockIdx.z;
    const int t = threadIdx.x;
    const int js = t >> 5, cc = t & 31;
    const int j = jg * 8 + js, c8 = cc * 8;
    float acc8[8];
    #pragma unroll
    for (int k = 0; k < 8; k++) acc8[k] = 0.f;
    for (int s = 0; s < 10; s++) {
        const int i = iq * 10 + s;
        frag_ab v = *(const frag_ab*)(hb + (size_t)(n * PP + i * WW + j) * CC + c8);
        #pragma unroll
        for (int k = 0; k < 8; k++) acc8[k] += b2f((u16)v[k]);
    }
    float* dst = Scolp + ((size_t)((iq * 8 + n) * HH + j)) * CC + c8;
    *(float4*)(dst)     = make_float4(acc8[0], acc8[1], acc8[2], acc8[3]);
    *(float4*)(dst + 4) = make_float4(acc8[4], acc8[5], acc8[6], acc8[7]);
}

// Scol[n][j][c] = sum of 8 Scolp slices.  Block (j, n); thread = c.
__global__ __launch_bounds__(256) void scolred_kernel(
    const float* __restrict__ Scolp, float* __restrict__ Scol)
{
    const int j = blockIdx.x, n = blockIdx.y;
    const int c = threadIdx.x;
    float s = 0.f;
    #pragma unroll
    for (int iq = 0; iq < 8; iq++)
        s += Scolp[((size_t)((iq * 8 + n) * HH + j)) * CC + c];
    Scol[(size_t)(n * HH + j) * CC + c] = s;
}

// depthwise 3x3 zero-pad in [p][c] layout.  ROUND-10 FORM (block (i, n),
// full j-sweep — keeps the 3-row halo block-local and L2-hot; round-11's
// j-split cost +13 MB HBM refetch).  8 channels/thread, 16B loads.
__global__ __launch_bounds__(256) void dw_kernel(
    const u16* __restrict__ gin, u16* __restrict__ dout,
    const float* __restrict__ wdw)
{
    __shared__ float sw[2304];   // [k][c]: sw[k*256+c] = wdw[c*9+k]
    const int i = blockIdx.x, n = blockIdx.y;
    const int t = threadIdx.x;
    for (int u = t; u < 2304; u += 256) {
        const int c = u / 9, k = u - c * 9;
        sw[k * 256 + c] = wdw[u];
    }
    __syncthreads();

    const int jg = t >> 5, cc = t & 31;
    const int gc = cc * 8;
    float4 wla[9], wlb[9];
    #pragma unroll
    for (int k = 0; k < 9; k++) {
        wla[k] = *(const float4*)(sw + k * 256 + gc);
        wlb[k] = *(const float4*)(sw + k * 256 + gc + 4);
    }

    const size_t nbase = (size_t)n * PP * CC;
    for (int s = 0; s < 10; s++) {
        const int j = jg + s * 8;
        float a0 = 0.f, a1 = 0.f, a2 = 0.f, a3 = 0.f;
        float a4 = 0.f, a5 = 0.f, a6 = 0.f, a7 = 0.f;
        #pragma unroll
        for (int di = -1; di <= 1; di++) {
            const int ii = i + di;
            if (ii < 0 || ii >= HH) continue;
            #pragma unroll
            for (int dj = -1; dj <= 1; dj++) {
                const int jj = j + dj;
                if (jj < 0 || jj >= WW) continue;
                frag_ab v = *(const frag_ab*)(gin + nbase + (size_t)(ii * WW + jj) * CC + gc);
                const int k = (di + 1) * 3 + (dj + 1);
                const float4 wa = wla[k], wb = wlb[k];
                a0 += wa.x * b2f((u16)v[0]); a1 += wa.y * b2f((u16)v[1]);
                a2 += wa.z * b2f((u16)v[2]); a3 += wa.w * b2f((u16)v[3]);
                a4 += wb.x * b2f((u16)v[4]); a5 += wb.y * b2f((u16)v[5]);
                a6 += wb.z * b2f((u16)v[6]); a7 += wb.w * b2f((u16)v[7]);
            }
        }
        frag_ab o;
        o[0] = (short)f2b(a0); o[1] = (short)f2b(a1);
        o[2] = (short)f2b(a2); o[3] = (short)f2b(a3);
        o[4] = (short)f2b(a4); o[5] = (short)f2b(a5);
        o[6] = (short)f2b(a6); o[7] = (short)f2b(a7);
        *(frag_ab*)(dout + nbase + (size_t)(i * WW + j) * CC + gc) = o;
    }
}

// GN2 + SiLU + transpose-out: Y [n][p][c] bf16 -> out [n][c][p] fp32.
__global__ __launch_bounds__(256) void gn2T_kernel(
    const u16* __restrict__ Y, float* __restrict__ out,
    const float* __restrict__ pscr,   // [800][32]
    const float* __restrict__ g2, const float* __restrict__ b2v)
{
    __shared__ u16 sT[64 * 72];
    __shared__ float sstat[32];
    const int p0 = blockIdx.x * 64, c0 = blockIdx.y * 64, n = blockIdx.z;
    const int t = threadIdx.x;
    if (t < 32) {
        const int kind = t >> 4, g = t & 15;
        const float* p = pscr + (size_t)(n * 100) * 32 + kind * 16 + g;
        float s = 0.f;
        #pragma unroll 4
        for (int ii = 0; ii < 100; ii++) s += p[ii * 32];
        sstat[t] = s;
    }
    {
        const int pl = t >> 2, cq = t & 3;
        const u16* row = Y + (size_t)(n * PP + p0 + pl) * CC + c0 + cq * 16;
        *(frag_ab*)(sT + pl * 72 + cq * 16)     = *(const frag_ab*)(row);
        *(frag_ab*)(sT + pl * 72 + cq * 16 + 8) = *(const frag_ab*)(row + 8);
    }
    __syncthreads();
    {
        const int cl = t >> 2, pq = t & 3;
        const int c = c0 + cl, g = c >> 4;
        const float su   = sstat[g];
        const float sq   = sstat[16 + g];
        const float mean = su * (1.f / GNCNT);
        const float var  = sq * (1.f / GNCNT) - mean * mean;
        const float inv  = rsqrtf(var + 1e-5f);
        const float a    = inv * g2[c];
        const float b    = b2v[c] - mean * a;
        float* orow = out + (size_t)(n * CC + c) * PP + p0 + pq * 16;
        #pragma unroll
        for (int u4 = 0; u4 < 4; u4++) {
            float4 o;
            float* op = (float*)&o;
            #pragma unroll
            for (int e = 0; e < 4; e++) {
                const int pp = pq * 16 + u4 * 4 + e;
                float xn = b2f(sT[pp * 72 + cl]) * a + b;
                op[e] = xn * sigf(xn);
            }
            ((float4*)(orow + u4 * 4))[0] = o;
        }
    }
}

extern "C" void kernel_launch(void* const* d_in, const int* in_sizes, int n_in,
                              void* d_out, int out_size, void* d_ws, size_t ws_size,
                              hipStream_t stream)
{
    const float* x      = (const float*)d_in[0];
    const float* w_pre  = (const float*)d_in[1];
    const float* g1     = (const float*)d_in[2];
    const float* b1     = (const float*)d_in[3];
    const float* w_gate = (const float*)d_in[4];
    const float* b_gate = (const float*)d_in[5];
    const float* w_dw   = (const float*)d_in[6];
    const float* w_pw   = (const float*)d_in[7];
    const float* g2     = (const float*)d_in[8];
    const float* b2     = (const float*)d_in[9];
    float* out = (float*)d_out;

    char* ws = (char*)d_ws;
    u16*   wb0   = (u16*)(ws);                      // 131,072 B
    u16*   wb1   = (u16*)(ws + 131072);             // 131,072 B
    u16*   wb2   = (u16*)(ws + 262144);             // 131,072 B
    float* Scolp = (float*)(ws + 393216);           // 5,242,880 B (8 slices)
    u16*   bufA  = (u16*)(ws + 26607616);           // 26,214,400 B
    u16*   bufB  = (u16*)(ws + 52822016);           // 26,214,400 B
    float* Srow  = (float*)(ws + 79036416);         // 655,360 B
    float* Scol  = (float*)(ws + 79691776);         // 655,360 B
    float* pscr0 = (float*)(ws + 80347136);         // 102,400 B
    float* pscr1 = (float*)(ws + 80449536);         // 102,400 B

    // weights (one launch)
    cvt3_kernel<<<192, 256, 0, stream>>>(w_pre, w_gate, w_pw, wb0, wb1, wb2);

    // conv1 (stages directly from fp32 x, transpose fused) + GN1 partial stats
    gemm0_kernel<<<800, 256, 0, stream>>>(wb0, bufA, pscr0, x);
    // GN1 + SiLU + Srow (c-split, 1280 blocks) -> hs in bufB
    gn1_kernel<<<dim3(80, 8, 2), 256, 0, stream>>>(bufA, bufB, Srow, pscr0, g1, b1);
    // Scol partial slices (8 slices, 640 blocks) + tiny reduce
    scol_kernel<<<dim3(10, 8, 8), 256, 0, stream>>>(bufB, Scolp);
    scolred_kernel<<<dim3(80, 8), 256, 0, stream>>>(Scolp, Scol);
    // gate conv + fused-scan gating (h from LDS tile) -> gated in bufA
    gemm1_kernel<<<800, 256, 0, stream>>>(bufB, wb1, bufA, Srow, Scol, b_gate);
    // depthwise 3x3 (round-10 form: block-local halo, L2-hot)
    dw_kernel<<<dim3(80, 8), 256, 0, stream>>>(bufA, bufB, w_dw);
    // conv3 + GN2 partial stats
    gemm2_kernel<<<800, 256, 0, stream>>>(bufB, wb2, bufA, pscr1);
    // GN2 + SiLU -> fp32 out (transposed; stats reduce inlined)
    gn2T_kernel<<<dim3(100, 4, 8), 256, 0, stream>>>(bufA, out, pscr1, g2, b2);
}